// Round 1
// baseline (2850.330 us; speedup 1.0000x reference)
//
#include <hip/hip_runtime.h>
#include <hip/hip_bf16.h>
#include <math.h>

#define D 128
#define BM 64
#define BN 128
#define BK 32

// ---------------------------------------------------------------------------
// Generic fp32 GEMM: out[r][c] = sum_k in(r,k) * w[c][k] + bias[c]
// in(r,k): k<128 -> in0[r*128+k], else in1[r*128+k-128]  (for A2 concat input)
// Tile 64 rows x 128 cols, BK=32, 256 threads, 8x4 register blocking.
// ---------------------------------------------------------------------------
__global__ __launch_bounds__(256) void gemm_node(
    const float* __restrict__ in0, const float* __restrict__ in1,
    const float* __restrict__ w, const float* __restrict__ bias,
    float* __restrict__ out, int R, int din)
{
    __shared__ float sIn[BM][BK + 1];
    __shared__ float sW[BN][BK + 1];
    const int tid = threadIdx.x;
    const int r0 = blockIdx.x * BM;
    const int cg = tid & 31;   // col group: cols cg*4 .. cg*4+3
    const int rg = tid >> 5;   // row group: rows rg*8 .. rg*8+7

    float acc[8][4] = {};

    for (int k0 = 0; k0 < din; k0 += BK) {
        // stage input tile 64x32 (coalesced along k)
#pragma unroll
        for (int l = 0; l < 8; ++l) {
            int lin = l * 256 + tid;
            int r = lin >> 5;
            int kk = lin & 31;
            int gr = r0 + r;
            float v = 0.f;
            if (gr < R) {
                int k = k0 + kk;
                v = (k < 128) ? in0[(size_t)gr * 128 + k]
                              : in1[(size_t)gr * 128 + (k - 128)];
            }
            sIn[r][kk] = v;
        }
        // stage weight tile 128x32
#pragma unroll
        for (int l = 0; l < 16; ++l) {
            int lin = l * 256 + tid;
            int c = lin >> 5;
            int kk = lin & 31;
            sW[c][kk] = w[(size_t)c * din + k0 + kk];
        }
        __syncthreads();
#pragma unroll
        for (int kk = 0; kk < BK; ++kk) {
            float a[8], b[4];
#pragma unroll
            for (int i = 0; i < 8; ++i) a[i] = sIn[rg * 8 + i][kk];
#pragma unroll
            for (int j = 0; j < 4; ++j) b[j] = sW[cg * 4 + j][kk];
#pragma unroll
            for (int i = 0; i < 8; ++i)
#pragma unroll
                for (int j = 0; j < 4; ++j)
                    acc[i][j] += a[i] * b[j];
        }
        __syncthreads();
    }

#pragma unroll
    for (int i = 0; i < 8; ++i) {
        int gr = r0 + rg * 8 + i;
        if (gr < R) {
#pragma unroll
            for (int j = 0; j < 4; ++j) {
                int c = cg * 4 + j;
                out[(size_t)gr * 128 + c] = acc[i][j] + bias[c];
            }
        }
    }
}

// ---------------------------------------------------------------------------
// Edge GEMM (B3 @ e) with fused epilogue:
//   hat = acc + B3b[c] + B1h[src[r]][c] + B2h[dst[r]][c]
//   hat_eta[r][c] = hat ; atomicAdd(sum_sigma[dst[r]][c], sigmoid(hat))
// ---------------------------------------------------------------------------
__global__ __launch_bounds__(256) void gemm_edge(
    const float* __restrict__ e, const float* __restrict__ w,
    const float* __restrict__ bias,
    const float* __restrict__ B1h, const float* __restrict__ B2h,
    const int* __restrict__ src, const int* __restrict__ dst,
    float* __restrict__ hat_eta, float* __restrict__ sum_sigma, int E)
{
    __shared__ float sIn[BM][BK + 1];
    __shared__ float sW[BN][BK + 1];
    __shared__ int sSrc[BM];
    __shared__ int sDst[BM];
    const int tid = threadIdx.x;
    const int r0 = blockIdx.x * BM;
    const int cg = tid & 31;
    const int rg = tid >> 5;

    if (tid < BM) {
        int gr = r0 + tid;
        sSrc[tid] = (gr < E) ? src[gr] : 0;
        sDst[tid] = (gr < E) ? dst[gr] : 0;
    }

    float acc[8][4] = {};

    for (int k0 = 0; k0 < 128; k0 += BK) {
#pragma unroll
        for (int l = 0; l < 8; ++l) {
            int lin = l * 256 + tid;
            int r = lin >> 5;
            int kk = lin & 31;
            int gr = r0 + r;
            sIn[r][kk] = (gr < E) ? e[(size_t)gr * 128 + k0 + kk] : 0.f;
        }
#pragma unroll
        for (int l = 0; l < 16; ++l) {
            int lin = l * 256 + tid;
            int c = lin >> 5;
            int kk = lin & 31;
            sW[c][kk] = w[(size_t)c * 128 + k0 + kk];
        }
        __syncthreads();
#pragma unroll
        for (int kk = 0; kk < BK; ++kk) {
            float a[8], b[4];
#pragma unroll
            for (int i = 0; i < 8; ++i) a[i] = sIn[rg * 8 + i][kk];
#pragma unroll
            for (int j = 0; j < 4; ++j) b[j] = sW[cg * 4 + j][kk];
#pragma unroll
            for (int i = 0; i < 8; ++i)
#pragma unroll
                for (int j = 0; j < 4; ++j)
                    acc[i][j] += a[i] * b[j];
        }
        __syncthreads();
    }

#pragma unroll
    for (int i = 0; i < 8; ++i) {
        int r = rg * 8 + i;
        int gr = r0 + r;
        if (gr < E) {
            int sn = sSrc[r];
            int dn = sDst[r];
#pragma unroll
            for (int j = 0; j < 4; ++j) {
                int c = cg * 4 + j;
                float v = acc[i][j] + bias[c] + B1h[(size_t)sn * 128 + c]
                          + B2h[(size_t)dn * 128 + c];
                hat_eta[(size_t)gr * 128 + c] = v;
                float sg = 1.f / (1.f + expf(-v));
                atomicAdd(&sum_sigma[(size_t)dn * 128 + c], sg);
            }
        }
    }
}

// ---------------------------------------------------------------------------
// Per-edge aggregation: eta = sigmoid(hat)/(sum_sigma[dst]+eps)
//   h_new[dst] += eta * A2hp[src] ; p_new[dst] += eta * C2p[src]
// Fused e-BN column stats (sum, sumsq of hat_eta).
// ---------------------------------------------------------------------------
__global__ __launch_bounds__(256) void edge_aggregate(
    const float* __restrict__ hat_eta, const float* __restrict__ sum_sigma,
    const float* __restrict__ A2hp, const float* __restrict__ C2p,
    const int* __restrict__ src, const int* __restrict__ dst,
    float* __restrict__ h_new, float* __restrict__ p_new,
    float* __restrict__ e_stats, int E)
{
    const int tid = threadIdx.x;
    const int d = tid & 127;
    const int half = tid >> 7;
    float s1 = 0.f, s2 = 0.f;
    for (int ed = blockIdx.x * 2 + half; ed < E; ed += gridDim.x * 2) {
        float he = hat_eta[(size_t)ed * 128 + d];
        s1 += he;
        s2 += he * he;
        float sg = 1.f / (1.f + expf(-he));
        int dn = dst[ed], sn = src[ed];
        float eta = sg / (sum_sigma[(size_t)dn * 128 + d] + 1e-6f);
        atomicAdd(&h_new[(size_t)dn * 128 + d], eta * A2hp[(size_t)sn * 128 + d]);
        atomicAdd(&p_new[(size_t)dn * 128 + d], eta * C2p[(size_t)sn * 128 + d]);
    }
    __shared__ float red[256];
    red[tid] = s1;
    __syncthreads();
    if (tid < 128) atomicAdd(&e_stats[d], red[tid] + red[tid + 128]);
    __syncthreads();
    red[tid] = s2;
    __syncthreads();
    if (tid < 128) atomicAdd(&e_stats[128 + d], red[tid] + red[tid + 128]);
}

// ---------------------------------------------------------------------------
// Column stats (sum, sumsq) over R rows of x[R,128] -> stats[0..127], [128..255]
// ---------------------------------------------------------------------------
__global__ __launch_bounds__(256) void col_stats(
    const float* __restrict__ x, float* __restrict__ stats, int R)
{
    const int tid = threadIdx.x;
    const int d = tid & 127;
    const int half = tid >> 7;
    float s1 = 0.f, s2 = 0.f;
    for (int r = blockIdx.x * 2 + half; r < R; r += gridDim.x * 2) {
        float v = x[(size_t)r * 128 + d];
        s1 += v;
        s2 += v * v;
    }
    __shared__ float red[256];
    red[tid] = s1;
    __syncthreads();
    if (tid < 128) atomicAdd(&stats[d], red[tid] + red[tid + 128]);
    __syncthreads();
    red[tid] = s2;
    __syncthreads();
    if (tid < 128) atomicAdd(&stats[128 + d], red[tid] + red[tid + 128]);
}

// ---------------------------------------------------------------------------
// out = resid + relu( g*(x-m)*rsqrt(v+eps) + b ), stats-driven BN (biased var)
// ---------------------------------------------------------------------------
__global__ __launch_bounds__(256) void finalize_bn_relu_res(
    const float* __restrict__ resid, const float* __restrict__ xnew,
    const float* __restrict__ stats, const float* __restrict__ g,
    const float* __restrict__ bb, float* __restrict__ out,
    size_t total, float invR)
{
    size_t idx = (size_t)blockIdx.x * 256 + threadIdx.x;
    if (idx >= total) return;
    int d = (int)(idx & 127);
    float m = stats[d] * invR;
    float var = stats[128 + d] * invR - m * m;
    if (var < 0.f) var = 0.f;
    float x = xnew[idx];
    float y = g[d] * (x - m) * rsqrtf(var + 1e-5f) + bb[d];
    y = y > 0.f ? y : 0.f;
    out[idx] = resid[idx] + y;
}

__global__ __launch_bounds__(256) void finalize_p(
    const float* __restrict__ p, const float* __restrict__ p_new,
    float* __restrict__ out, size_t total)
{
    size_t idx = (size_t)blockIdx.x * 256 + threadIdx.x;
    if (idx >= total) return;
    out[idx] = p[idx] + tanhf(p_new[idx]);
}

// ---------------------------------------------------------------------------
extern "C" void kernel_launch(void* const* d_in, const int* in_sizes, int n_in,
                              void* d_out, int out_size, void* d_ws, size_t ws_size,
                              hipStream_t stream)
{
    const float* h   = (const float*)d_in[0];
    const float* e   = (const float*)d_in[1];
    const float* p   = (const float*)d_in[2];
    const int* src   = (const int*)d_in[3];
    const int* dst   = (const int*)d_in[4];
    const float* A1w = (const float*)d_in[5];
    const float* A1b = (const float*)d_in[6];
    const float* A2w = (const float*)d_in[7];
    const float* A2b = (const float*)d_in[8];
    const float* B1w = (const float*)d_in[9];
    const float* B1b = (const float*)d_in[10];
    const float* B2w = (const float*)d_in[11];
    const float* B2b = (const float*)d_in[12];
    const float* B3w = (const float*)d_in[13];
    const float* B3b = (const float*)d_in[14];
    const float* C1w = (const float*)d_in[15];
    const float* C1b = (const float*)d_in[16];
    const float* C2w = (const float*)d_in[17];
    const float* C2b = (const float*)d_in[18];
    const float* bn_h_g = (const float*)d_in[19];
    const float* bn_h_b = (const float*)d_in[20];
    const float* bn_e_g = (const float*)d_in[21];
    const float* bn_e_b = (const float*)d_in[22];

    const int N = in_sizes[0] / D;   // 50000
    const int E = in_sizes[3];       // 600000
    const size_t ND = (size_t)N * D;
    const size_t ED = (size_t)E * D;

    float* out_h = (float*)d_out;
    float* out_e = out_h + ND;       // hat_eta lives here until finalize_e
    float* out_p = out_e + ED;

    float* ws = (float*)d_ws;
    float* B1h       = ws;
    float* B2h       = B1h + ND;
    float* A2hp      = B2h + ND;
    float* C2p       = A2hp + ND;
    float* h_new     = C2p + ND;
    float* p_new     = h_new + ND;
    float* sum_sigma = p_new + ND;
    float* h_stats   = sum_sigma + ND;  // 256 floats
    float* e_stats   = h_stats + 256;   // 256 floats

    // zero: sum_sigma + h_stats + e_stats (contiguous)
    hipMemsetAsync(sum_sigma, 0, (ND + 512) * sizeof(float), stream);

    const int gN = (N + BM - 1) / BM;
    const int gE = (E + BM - 1) / BM;

    // node linears
    gemm_node<<<gN, 256, 0, stream>>>(h, nullptr, A1w, A1b, h_new, N, 128);
    gemm_node<<<gN, 256, 0, stream>>>(h, nullptr, B1w, B1b, B1h, N, 128);
    gemm_node<<<gN, 256, 0, stream>>>(h, nullptr, B2w, B2b, B2h, N, 128);
    gemm_node<<<gN, 256, 0, stream>>>(p, nullptr, C1w, C1b, p_new, N, 128);
    gemm_node<<<gN, 256, 0, stream>>>(p, nullptr, C2w, C2b, C2p, N, 128);
    gemm_node<<<gN, 256, 0, stream>>>(h, p, A2w, A2b, A2hp, N, 256);

    // edge linear + hat_eta + sigma scatter
    gemm_edge<<<gE, 256, 0, stream>>>(e, B3w, B3b, B1h, B2h, src, dst,
                                      out_e, sum_sigma, E);

    // eta scatter + e-BN stats
    edge_aggregate<<<2048, 256, 0, stream>>>(out_e, sum_sigma, A2hp, C2p,
                                             src, dst, h_new, p_new, e_stats, E);

    // h-BN stats
    col_stats<<<1024, 256, 0, stream>>>(h_new, h_stats, N);

    // finalizers
    {
        size_t total = ND;
        int blocks = (int)((total + 255) / 256);
        finalize_bn_relu_res<<<blocks, 256, 0, stream>>>(
            h, h_new, h_stats, bn_h_g, bn_h_b, out_h, total, 1.f / (float)N);
        finalize_p<<<blocks, 256, 0, stream>>>(p, p_new, out_p, total);
    }
    {
        size_t total = ED;
        int blocks = (int)((total + 255) / 256);
        finalize_bn_relu_res<<<blocks, 256, 0, stream>>>(
            e, out_e, e_stats, bn_e_g, bn_e_b, out_e, total, 1.f / (float)E);
    }
}